// Round 5
// baseline (915.960 us; speedup 1.0000x reference)
//
#include <hip/hip_runtime.h>
#include <hip/hip_bf16.h>

// LSTM decoder: 12 steps, batch 32768, hidden 256, input 64, TF=1.
// One persistent block per 128 batch rows (256 blocks = 256 CUs).
// h double-buffered in LDS (bf16), c pinned in AGPRs, W packed bf16 from L2.
// TRANSPOSED mfma (A=weights, B=h) -> lane owns 4 contiguous units.
// GATE-PAIR SPLIT: pass A (i,f) -> partial cell update; pass B (g,o) ->
// finish. Halves live accumulators (64 not 128) so 256-reg budget fits
// with zero scratch spill. Out-projection done as MFMA (W_hp as A).

#define PRED_LEN 12
#define BATCH    32768
#define HID      256
#define IDIM     64
#define KTOT     320      // 256 (h) + 64 (x)
#define G4       1024     // 4*HID gate rows
#define BROWS    128      // batch rows per block
#define HSTR     264      // padded bf16 row stride (33 quads -> conflict-free b128)
#define XSTR     72       // padded bf16 row stride for x (9 quads)

#define DYN_LDS  ((2 * BROWS * HSTR + BROWS * XSTR) * 2)   // 153600 B

typedef short s16x8 __attribute__((ext_vector_type(8)));  // 8 x bf16 (MFMA frag)
typedef short s16x4 __attribute__((ext_vector_type(4)));
typedef float f32x4 __attribute__((ext_vector_type(4)));  // MFMA accum frag

static __device__ __forceinline__ float sigmoid_f(float x) {
    return 1.0f / (1.0f + __expf(-x));
}
static __device__ __forceinline__ float tanh_f(float x) {
    return 1.0f - 2.0f / (__expf(2.0f * x) + 1.0f);
}
static __device__ __forceinline__ unsigned short f2bf(float x) {
    __hip_bfloat16 h = __float2bfloat16(x);
    return *reinterpret_cast<unsigned short*>(&h);
}

// Pin persistent cell state into the AGPR bank so it can't spill to scratch.
static __device__ __forceinline__ void ag_write(float& dst, float v) {
    asm("v_accvgpr_write_b32 %0, %1" : "=a"(dst) : "v"(v));
}
static __device__ __forceinline__ float ag_read(float src) {
    float r;
    asm("v_accvgpr_read_b32 %0, %1" : "=v"(r) : "a"(src));
    return r;
}

// Pack W = [W_hh | W_ih] as bf16 row-major [1024][320]; bcomb = b_ih + b_hh.
__global__ void prep_kernel(const float* __restrict__ W_ih,
                            const float* __restrict__ W_hh,
                            const float* __restrict__ b_ih,
                            const float* __restrict__ b_hh,
                            unsigned short* __restrict__ Wp,
                            float* __restrict__ bcomb) {
    int gid = blockIdx.x * 256 + threadIdx.x;
    if (gid < G4 * KTOT) {
        int n = gid / KTOT;
        int k = gid - n * KTOT;
        float v = (k < HID) ? W_hh[n * HID + k] : W_ih[n * IDIM + (k - HID)];
        Wp[gid] = f2bf(v);
    }
    if (gid < G4) bcomb[gid] = b_ih[gid] + b_hh[gid];
}

__global__ __launch_bounds__(512, 2) void lstm_kernel(
    const float* __restrict__ gr,      // (13, B, 2)
    const float* __restrict__ h0g,     // (B, 256)
    const unsigned short* __restrict__ Wp,   // (1024, 320) bf16
    const float* __restrict__ bcomb,   // (1024,)
    const float* __restrict__ W_hp,    // (2, 256)
    const float* __restrict__ b_hp,    // (2,)
    const float* __restrict__ W_emb,   // (64, 2)
    const float* __restrict__ b_emb,   // (64,)
    float* __restrict__ out)           // (12, B, 2)
{
    extern __shared__ unsigned short smem[];
    unsigned short* hb0 = smem;                        // [BROWS][HSTR]
    unsigned short* hb1 = smem + BROWS * HSTR;
    unsigned short* xb  = smem + 2 * BROWS * HSTR;     // [BROWS][XSTR]

    __shared__ float sWe0[IDIM], sWe1[IDIM], sBe[IDIM];
    // W_hp as bf16, 2 rows padded to HSTR for conflict-free b128 A-frag reads
    __shared__ unsigned short sWhpb[2 * HSTR];
    // per-wave transposed bias table: [wave][ch][g][u] u=lq*4+r (16)
    __shared__ float sBiasT[8 * 2 * 4 * 16];

    const int tid  = threadIdx.x;
    const int wave = tid >> 6;
    const int lane = tid & 63;
    const int l15  = lane & 15;
    const int lq   = lane >> 4;
    const int row0 = blockIdx.x * BROWS;

    if (tid < IDIM) {
        sWe0[tid] = W_emb[tid * 2 + 0];
        sWe1[tid] = W_emb[tid * 2 + 1];
        sBe[tid]  = b_emb[tid];
    }
    // stage W_hp -> bf16 (512 threads == 2*256 elements)
    {
        int r = tid >> 8, c = tid & 255;
        sWhpb[r * HSTR + c] = f2bf(W_hp[r * HID + c]);
    }
    // stage transposed bias: value(w,ch,g,u) = bcomb[g*256 + ch*128 + w*16 + u]
#pragma unroll
    for (int j = tid; j < 8 * 2 * 4 * 16; j += 512) {
        int w   = j >> 7;
        int rem = j & 127;
        int ch  = rem >> 6;
        int g   = (rem >> 4) & 3;
        int u   = rem & 15;
        sBiasT[j] = bcomb[g * HID + ch * 128 + w * 16 + u];
    }

    const float bhp0 = b_hp[0];
    const float bhp1 = b_hp[1];

    // stage h0 (fp32 global -> bf16 LDS hb0)
#pragma unroll
    for (int j = 0; j < 16; ++j) {
        int idx = j * 2048 + tid * 4;
        const float4 v = *reinterpret_cast<const float4*>(&h0g[row0 * HID + idx]);
        int r = idx >> 8;
        int c = idx & 255;
        s16x4 pk;
        pk[0] = (short)f2bf(v.x); pk[1] = (short)f2bf(v.y);
        pk[2] = (short)f2bf(v.z); pk[3] = (short)f2bf(v.w);
        *reinterpret_cast<s16x4*>(&hb0[r * HSTR + c]) = pk;
    }

    // inline embedding: x[t] = gr[t+1] @ W_emb^T + b_emb  -> bf16 LDS
    auto stage_x = [&](int tt) {
        const int rr = tid >> 2;
        const int d0 = (tid & 3) * 16;
        const float2 g2 = *reinterpret_cast<const float2*>(
            &gr[(((size_t)(tt + 1)) * BATCH + row0 + rr) * 2]);
        s16x8 v0, v1;
#pragma unroll
        for (int e = 0; e < 8; ++e) {
            int d = d0 + e;
            v0[e] = (short)f2bf(g2.x * sWe0[d] + g2.y * sWe1[d] + sBe[d]);
        }
#pragma unroll
        for (int e = 0; e < 8; ++e) {
            int d = d0 + 8 + e;
            v1[e] = (short)f2bf(g2.x * sWe0[d] + g2.y * sWe1[d] + sBe[d]);
        }
        *reinterpret_cast<s16x8*>(&xb[rr * XSTR + d0])     = v0;
        *reinterpret_cast<s16x8*>(&xb[rr * XSTR + d0 + 8]) = v1;
    };

    __syncthreads();      // staging visible
    stage_x(0);
    __syncthreads();

    // persistent cell state, fp32, PINNED in AGPRs. Index (ch*8+m)*4+r.
    float cst[64];
#pragma unroll
    for (int i = 0; i < 64; ++i) ag_write(cst[i], 0.0f);

    const unsigned short* wb = Wp + (wave * 16 + l15) * KTOT + lq * 8;

    unsigned short* hread  = hb0;
    unsigned short* hwrite = hb1;

    for (int t = 0; t < PRED_LEN; ++t) {
        const unsigned short* hA = hread + l15 * HSTR + lq * 8;
        const unsigned short* xA = xb + l15 * XSTR + lq * 8;

#pragma unroll
        for (int ch = 0; ch < 2; ++ch) {
            const float* bt = &sBiasT[(wave * 2 + ch) * 64 + lq * 4];
            float si[32];   // sigmoid(i) carried pass A -> pass B (VGPRs)

            // ================= pass A : gates i (g=0), f (g=1) =================
            {
                f32x4 acc[8][2];
#pragma unroll
                for (int g = 0; g < 2; ++g) {
                    f32x4 b4 = *reinterpret_cast<const f32x4*>(&bt[g * 16]);
#pragma unroll
                    for (int m = 0; m < 8; ++m) acc[m][g] = b4;
                }
#pragma unroll
                for (int kf = 0; kf < 10; ++kf) {
                    s16x8 wfr[2];
#pragma unroll
                    for (int g = 0; g < 2; ++g)
                        wfr[g] = *reinterpret_cast<const s16x8*>(
                            &wb[(g * HID + ch * 128) * KTOT + kf * 32]);
#pragma unroll
                    for (int m = 0; m < 8; ++m) {
                        s16x8 afr;
                        if (kf < 8)
                            afr = *reinterpret_cast<const s16x8*>(
                                &hA[m * 16 * HSTR + kf * 32]);
                        else
                            afr = *reinterpret_cast<const s16x8*>(
                                &xA[m * 16 * XSTR + (kf - 8) * 32]);
#pragma unroll
                        for (int g = 0; g < 2; ++g)
                            acc[m][g] = __builtin_amdgcn_mfma_f32_16x16x32_bf16(
                                wfr[g], afr, acc[m][g], 0, 0, 0);
                    }
                }
                // partial cell update: c <- sigmoid(f)*c ; si = sigmoid(i)
#pragma unroll
                for (int m = 0; m < 8; ++m)
#pragma unroll
                    for (int r = 0; r < 4; ++r) {
                        int ci = (ch * 8 + m) * 4 + r;
                        float cold = ag_read(cst[ci]);
                        ag_write(cst[ci], sigmoid_f(acc[m][1][r]) * cold);
                        si[m * 4 + r] = sigmoid_f(acc[m][0][r]);
                    }
            }

            // ================= pass B : gates g (g=2), o (g=3) =================
            {
                f32x4 acc[8][2];
#pragma unroll
                for (int g = 0; g < 2; ++g) {
                    f32x4 b4 = *reinterpret_cast<const f32x4*>(&bt[(2 + g) * 16]);
#pragma unroll
                    for (int m = 0; m < 8; ++m) acc[m][g] = b4;
                }
#pragma unroll
                for (int kf = 0; kf < 10; ++kf) {
                    s16x8 wfr[2];
#pragma unroll
                    for (int g = 0; g < 2; ++g)
                        wfr[g] = *reinterpret_cast<const s16x8*>(
                            &wb[((2 + g) * HID + ch * 128) * KTOT + kf * 32]);
#pragma unroll
                    for (int m = 0; m < 8; ++m) {
                        s16x8 afr;
                        if (kf < 8)
                            afr = *reinterpret_cast<const s16x8*>(
                                &hA[m * 16 * HSTR + kf * 32]);
                        else
                            afr = *reinterpret_cast<const s16x8*>(
                                &xA[m * 16 * XSTR + (kf - 8) * 32]);
#pragma unroll
                        for (int g = 0; g < 2; ++g)
                            acc[m][g] = __builtin_amdgcn_mfma_f32_16x16x32_bf16(
                                wfr[g], afr, acc[m][g], 0, 0, 0);
                    }
                }
                // finish: cn = c_partial + si*tanh(g); h = sigmoid(o)*tanh(cn)
                const int nbase = ch * 128 + wave * 16 + lq * 4;
#pragma unroll
                for (int m = 0; m < 8; ++m) {
                    s16x4 hp;
#pragma unroll
                    for (int r = 0; r < 4; ++r) {
                        int ci = (ch * 8 + m) * 4 + r;
                        float cn = ag_read(cst[ci]) +
                                   si[m * 4 + r] * tanh_f(acc[m][0][r]);
                        ag_write(cst[ci], cn);
                        hp[r] = (short)f2bf(sigmoid_f(acc[m][1][r]) * tanh_f(cn));
                    }
                    *reinterpret_cast<s16x4*>(
                        &hwrite[(m * 16 + l15) * HSTR + nbase]) = hp;
                }
            }
        }
        __syncthreads();   // h_new complete; old h/x reads complete

        // out[t] = h_new @ W_hp^T + b_hp via MFMA (A = W_hp rows 0..1, rest junk)
        {
            f32x4 po = (f32x4){0.f, 0.f, 0.f, 0.f};
            const unsigned short* hB = hwrite + (wave * 16 + l15) * HSTR + lq * 8;
            const unsigned short* aW = sWhpb + (l15 & 1) * HSTR + lq * 8;
#pragma unroll
            for (int kf = 0; kf < 8; ++kf) {
                s16x8 a = *reinterpret_cast<const s16x8*>(&aW[kf * 32]);
                s16x8 b = *reinterpret_cast<const s16x8*>(&hB[kf * 32]);
                po = __builtin_amdgcn_mfma_f32_16x16x32_bf16(a, b, po, 0, 0, 0);
            }
            if (lq == 0) {   // D rows 0,1 = out channels; col = batch (l15)
                float2 o2 = make_float2(po[0] + bhp0, po[1] + bhp1);
                *reinterpret_cast<float2*>(
                    &out[((size_t)t * BATCH + row0 + wave * 16 + l15) * 2]) = o2;
            }
        }

        if (t + 1 < PRED_LEN) stage_x(t + 1);
        __syncthreads();   // x[t+1] staged; h_new reads complete

        unsigned short* tmp = hread; hread = hwrite; hwrite = tmp;
    }
}

extern "C" void kernel_launch(void* const* d_in, const int* in_sizes, int n_in,
                              void* d_out, int out_size, void* d_ws, size_t ws_size,
                              hipStream_t stream) {
    const float* gr    = (const float*)d_in[0];
    const float* h0    = (const float*)d_in[1];
    const float* W_ih  = (const float*)d_in[2];
    const float* W_hh  = (const float*)d_in[3];
    const float* b_ih  = (const float*)d_in[4];
    const float* b_hh  = (const float*)d_in[5];
    const float* W_hp  = (const float*)d_in[6];
    const float* b_hp  = (const float*)d_in[7];
    const float* W_emb = (const float*)d_in[8];
    const float* b_emb = (const float*)d_in[9];
    float* out = (float*)d_out;

    unsigned short* Wp = (unsigned short*)d_ws;
    float* bcomb = (float*)((char*)d_ws + (size_t)G4 * KTOT * sizeof(unsigned short));

    prep_kernel<<<(G4 * KTOT) / 256, 256, 0, stream>>>(W_ih, W_hh, b_ih, b_hh, Wp, bcomb);

    (void)hipFuncSetAttribute((const void*)lstm_kernel,
                              hipFuncAttributeMaxDynamicSharedMemorySize, DYN_LDS);

    lstm_kernel<<<BATCH / BROWS, 512, DYN_LDS, stream>>>(
        gr, h0, Wp, bcomb, W_hp, b_hp, W_emb, b_emb, out);
}

// Round 6
// 503.520 us; speedup vs baseline: 1.8191x; 1.8191x over previous
//
#include <hip/hip_runtime.h>
#include <hip/hip_bf16.h>

// LSTM decoder: 12 steps, batch 32768, hidden 256, input 64, TF=1.
// One persistent block per 128 batch rows (256 blocks = 256 CUs).
// h double-buffered in LDS (bf16), c pinned in AGPRs, weights repacked into
// a PER-WAVE CONTIGUOUS stream (WpT) read via a single walking pointer
// (#pragma unroll 1 on the K loop) so no giant hoisted address sets ->
// no scratch spill. TRANSPOSED mfma (A=weights, B=h); gate-pair split
// (i,f then g,o) keeps live accumulators at 64. Out-projection via MFMA.

#define PRED_LEN 12
#define BATCH    32768
#define HID      256
#define IDIM     64
#define KTOT     320      // 256 (h) + 64 (x)
#define G4       1024     // 4*HID gate rows
#define BROWS    128      // batch rows per block
#define HSTR     264      // padded bf16 row stride (33 quads -> conflict-free b128)
#define XSTR     72       // padded bf16 row stride for x (9 quads)

#define DYN_LDS  ((2 * BROWS * HSTR + BROWS * XSTR) * 2)   // 153600 B

typedef short s16x8 __attribute__((ext_vector_type(8)));  // 8 x bf16 (MFMA frag)
typedef short s16x4 __attribute__((ext_vector_type(4)));
typedef float f32x4 __attribute__((ext_vector_type(4)));  // MFMA accum frag

static __device__ __forceinline__ float sigmoid_f(float x) {
    return 1.0f / (1.0f + __expf(-x));
}
static __device__ __forceinline__ float tanh_f(float x) {
    return 1.0f - 2.0f / (__expf(2.0f * x) + 1.0f);
}
static __device__ __forceinline__ unsigned short f2bf(float x) {
    __hip_bfloat16 h = __float2bfloat16(x);
    return *reinterpret_cast<unsigned short*>(&h);
}

// Pin persistent cell state into the AGPR bank.
static __device__ __forceinline__ void ag_write(float& dst, float v) {
    asm("v_accvgpr_write_b32 %0, %1" : "=a"(dst) : "v"(v));
}
static __device__ __forceinline__ float ag_read(float src) {
    float r;
    asm("v_accvgpr_read_b32 %0, %1" : "=v"(r) : "a"(src));
    return r;
}

// Repack weights into per-wave contiguous MFMA-fragment stream:
// WpT short index = (((w*10 + kf)*8 + ch*4 + g)*64 + lane)*8 + e
// value = W[(g*256 + ch*128 + w*16 + (lane&15)) , k] with k = kf*32 + (lane>>4)*8 + e,
// W = [W_hh | W_ih] along k. Total 327680 shorts = 640 KB.
__global__ void prep_kernel(const float* __restrict__ W_ih,
                            const float* __restrict__ W_hh,
                            const float* __restrict__ b_ih,
                            const float* __restrict__ b_hh,
                            unsigned short* __restrict__ WpT,
                            float* __restrict__ bcomb) {
    int gid = blockIdx.x * 256 + threadIdx.x;     // 0 .. 327679
    int w    = gid / 40960;
    int r1   = gid - w * 40960;
    int kf   = r1 >> 12;
    int r2   = r1 & 4095;
    int cg   = r2 >> 9;                           // ch*4 + g
    int ch   = cg >> 2, g = cg & 3;
    int lane = (r2 >> 3) & 63;
    int e    = r2 & 7;
    int n    = g * 256 + ch * 128 + w * 16 + (lane & 15);
    int k    = kf * 32 + (lane >> 4) * 8 + e;
    float v  = (k < HID) ? W_hh[n * HID + k] : W_ih[n * IDIM + (k - HID)];
    WpT[gid] = f2bf(v);
    if (gid < G4) bcomb[gid] = b_ih[gid] + b_hh[gid];
}

__global__ __launch_bounds__(512, 2) void lstm_kernel(
    const float* __restrict__ gr,      // (13, B, 2)
    const float* __restrict__ h0g,     // (B, 256)
    const unsigned short* __restrict__ WpT,  // packed fragment stream
    const float* __restrict__ bcomb,   // (1024,)
    const float* __restrict__ W_hp,    // (2, 256)
    const float* __restrict__ b_hp,    // (2,)
    const float* __restrict__ W_emb,   // (64, 2)
    const float* __restrict__ b_emb,   // (64,)
    float* __restrict__ out)           // (12, B, 2)
{
    extern __shared__ unsigned short smem[];
    unsigned short* hb0 = smem;                        // [BROWS][HSTR]
    unsigned short* hb1 = smem + BROWS * HSTR;
    unsigned short* xb  = smem + 2 * BROWS * HSTR;     // [BROWS][XSTR]

    __shared__ float sWe0[IDIM], sWe1[IDIM], sBe[IDIM];
    __shared__ unsigned short sWhpb[2 * HSTR];
    __shared__ float sBiasT[8 * 2 * 4 * 16];  // [wave][ch][g][u]

    const int tid  = threadIdx.x;
    const int wave = tid >> 6;
    const int lane = tid & 63;
    const int l15  = lane & 15;
    const int lq   = lane >> 4;
    const int row0 = blockIdx.x * BROWS;

    if (tid < IDIM) {
        sWe0[tid] = W_emb[tid * 2 + 0];
        sWe1[tid] = W_emb[tid * 2 + 1];
        sBe[tid]  = b_emb[tid];
    }
    {
        int r = tid >> 8, c = tid & 255;
        sWhpb[r * HSTR + c] = f2bf(W_hp[r * HID + c]);
    }
#pragma unroll
    for (int j = tid; j < 8 * 2 * 4 * 16; j += 512) {
        int w   = j >> 7;
        int rem = j & 127;
        int ch  = rem >> 6;
        int g   = (rem >> 4) & 3;
        int u   = rem & 15;
        sBiasT[j] = bcomb[g * HID + ch * 128 + w * 16 + u];
    }

    const float bhp0 = b_hp[0];
    const float bhp1 = b_hp[1];

    // stage h0 (fp32 global -> bf16 LDS hb0)
#pragma unroll
    for (int j = 0; j < 16; ++j) {
        int idx = j * 2048 + tid * 4;
        const float4 v = *reinterpret_cast<const float4*>(&h0g[row0 * HID + idx]);
        int r = idx >> 8;
        int c = idx & 255;
        s16x4 pk;
        pk[0] = (short)f2bf(v.x); pk[1] = (short)f2bf(v.y);
        pk[2] = (short)f2bf(v.z); pk[3] = (short)f2bf(v.w);
        *reinterpret_cast<s16x4*>(&hb0[r * HSTR + c]) = pk;
    }

    // inline embedding: x[t] = gr[t+1] @ W_emb^T + b_emb  -> bf16 LDS
    auto stage_x = [&](int tt) {
        const int rr = tid >> 2;
        const int d0 = (tid & 3) * 16;
        const float2 g2 = *reinterpret_cast<const float2*>(
            &gr[(((size_t)(tt + 1)) * BATCH + row0 + rr) * 2]);
        s16x8 v0, v1;
#pragma unroll
        for (int e = 0; e < 8; ++e) {
            int d = d0 + e;
            v0[e] = (short)f2bf(g2.x * sWe0[d] + g2.y * sWe1[d] + sBe[d]);
        }
#pragma unroll
        for (int e = 0; e < 8; ++e) {
            int d = d0 + 8 + e;
            v1[e] = (short)f2bf(g2.x * sWe0[d] + g2.y * sWe1[d] + sBe[d]);
        }
        *reinterpret_cast<s16x8*>(&xb[rr * XSTR + d0])     = v0;
        *reinterpret_cast<s16x8*>(&xb[rr * XSTR + d0 + 8]) = v1;
    };

    __syncthreads();
    stage_x(0);
    __syncthreads();

    // persistent cell state, fp32, pinned in AGPRs. Index (ch*8+m)*4+r.
    float cst[64];
#pragma unroll
    for (int i = 0; i < 64; ++i) ag_write(cst[i], 0.0f);

    // per-wave fragment stream base (s16x8 units)
    const s16x8* wv = reinterpret_cast<const s16x8*>(WpT) + wave * 5120 + lane;

    unsigned short* hread  = hb0;
    unsigned short* hwrite = hb1;

    for (int t = 0; t < PRED_LEN; ++t) {
        const unsigned short* hA = hread + l15 * HSTR + lq * 8;
        const unsigned short* xA = xb + l15 * XSTR + lq * 8;

#pragma unroll
        for (int ch = 0; ch < 2; ++ch) {
            const float* bt = &sBiasT[(wave * 2 + ch) * 64 + lq * 4];
            float si[32];   // sigmoid(i) carried pass A -> pass B

            // ===== pass A : gates i (0), f (1) =====
            {
                f32x4 acc[8][2];
#pragma unroll
                for (int g = 0; g < 2; ++g) {
                    f32x4 b4 = *reinterpret_cast<const f32x4*>(&bt[g * 16]);
#pragma unroll
                    for (int m = 0; m < 8; ++m) acc[m][g] = b4;
                }
                const s16x8* wp = wv + (ch * 4) * 64;
#pragma unroll 1
                for (int kf = 0; kf < 8; ++kf) {
                    s16x8 w0 = wp[0];
                    s16x8 w1 = wp[64];
                    wp += 512;
                    const unsigned short* ha = hA + kf * 32;
#pragma unroll
                    for (int m = 0; m < 8; ++m) {
                        s16x8 afr = *reinterpret_cast<const s16x8*>(&ha[m * 16 * HSTR]);
                        acc[m][0] = __builtin_amdgcn_mfma_f32_16x16x32_bf16(w0, afr, acc[m][0], 0, 0, 0);
                        acc[m][1] = __builtin_amdgcn_mfma_f32_16x16x32_bf16(w1, afr, acc[m][1], 0, 0, 0);
                    }
                }
#pragma unroll
                for (int kx = 0; kx < 2; ++kx) {
                    s16x8 w0 = wp[0];
                    s16x8 w1 = wp[64];
                    wp += 512;
#pragma unroll
                    for (int m = 0; m < 8; ++m) {
                        s16x8 afr = *reinterpret_cast<const s16x8*>(&xA[m * 16 * XSTR + kx * 32]);
                        acc[m][0] = __builtin_amdgcn_mfma_f32_16x16x32_bf16(w0, afr, acc[m][0], 0, 0, 0);
                        acc[m][1] = __builtin_amdgcn_mfma_f32_16x16x32_bf16(w1, afr, acc[m][1], 0, 0, 0);
                    }
                }
                // partial cell update: c <- sigmoid(f)*c ; si = sigmoid(i)
#pragma unroll
                for (int m = 0; m < 8; ++m)
#pragma unroll
                    for (int r = 0; r < 4; ++r) {
                        int ci = (ch * 8 + m) * 4 + r;
                        float cold = ag_read(cst[ci]);
                        ag_write(cst[ci], sigmoid_f(acc[m][1][r]) * cold);
                        si[m * 4 + r] = sigmoid_f(acc[m][0][r]);
                    }
            }

            // ===== pass B : gates g (2), o (3) =====
            {
                f32x4 acc[8][2];
#pragma unroll
                for (int g = 0; g < 2; ++g) {
                    f32x4 b4 = *reinterpret_cast<const f32x4*>(&bt[(2 + g) * 16]);
#pragma unroll
                    for (int m = 0; m < 8; ++m) acc[m][g] = b4;
                }
                const s16x8* wp = wv + (ch * 4 + 2) * 64;
#pragma unroll 1
                for (int kf = 0; kf < 8; ++kf) {
                    s16x8 w0 = wp[0];
                    s16x8 w1 = wp[64];
                    wp += 512;
                    const unsigned short* ha = hA + kf * 32;
#pragma unroll
                    for (int m = 0; m < 8; ++m) {
                        s16x8 afr = *reinterpret_cast<const s16x8*>(&ha[m * 16 * HSTR]);
                        acc[m][0] = __builtin_amdgcn_mfma_f32_16x16x32_bf16(w0, afr, acc[m][0], 0, 0, 0);
                        acc[m][1] = __builtin_amdgcn_mfma_f32_16x16x32_bf16(w1, afr, acc[m][1], 0, 0, 0);
                    }
                }
#pragma unroll
                for (int kx = 0; kx < 2; ++kx) {
                    s16x8 w0 = wp[0];
                    s16x8 w1 = wp[64];
                    wp += 512;
#pragma unroll
                    for (int m = 0; m < 8; ++m) {
                        s16x8 afr = *reinterpret_cast<const s16x8*>(&xA[m * 16 * XSTR + kx * 32]);
                        acc[m][0] = __builtin_amdgcn_mfma_f32_16x16x32_bf16(w0, afr, acc[m][0], 0, 0, 0);
                        acc[m][1] = __builtin_amdgcn_mfma_f32_16x16x32_bf16(w1, afr, acc[m][1], 0, 0, 0);
                    }
                }
                // finish: cn = c_partial + si*tanh(g); h = sigmoid(o)*tanh(cn)
                const int nbase = ch * 128 + wave * 16 + lq * 4;
#pragma unroll
                for (int m = 0; m < 8; ++m) {
                    s16x4 hp;
#pragma unroll
                    for (int r = 0; r < 4; ++r) {
                        int ci = (ch * 8 + m) * 4 + r;
                        float cn = ag_read(cst[ci]) +
                                   si[m * 4 + r] * tanh_f(acc[m][0][r]);
                        ag_write(cst[ci], cn);
                        hp[r] = (short)f2bf(sigmoid_f(acc[m][1][r]) * tanh_f(cn));
                    }
                    *reinterpret_cast<s16x4*>(
                        &hwrite[(m * 16 + l15) * HSTR + nbase]) = hp;
                }
            }
        }
        __syncthreads();   // h_new complete; old h/x reads complete

        // out[t] = h_new @ W_hp^T + b_hp via MFMA (A rows 0,1 = channels)
        {
            f32x4 po = (f32x4){0.f, 0.f, 0.f, 0.f};
            const unsigned short* hB = hwrite + (wave * 16 + l15) * HSTR + lq * 8;
            const unsigned short* aW = sWhpb + (l15 & 1) * HSTR + lq * 8;
#pragma unroll
            for (int kf = 0; kf < 8; ++kf) {
                s16x8 a = *reinterpret_cast<const s16x8*>(&aW[kf * 32]);
                s16x8 b = *reinterpret_cast<const s16x8*>(&hB[kf * 32]);
                po = __builtin_amdgcn_mfma_f32_16x16x32_bf16(a, b, po, 0, 0, 0);
            }
            if (lq == 0) {
                float2 o2 = make_float2(po[0] + bhp0, po[1] + bhp1);
                *reinterpret_cast<float2*>(
                    &out[((size_t)t * BATCH + row0 + wave * 16 + l15) * 2]) = o2;
            }
        }

        if (t + 1 < PRED_LEN) stage_x(t + 1);
        __syncthreads();   // x[t+1] staged; h_new reads complete

        unsigned short* tmp = hread; hread = hwrite; hwrite = tmp;
    }
}

extern "C" void kernel_launch(void* const* d_in, const int* in_sizes, int n_in,
                              void* d_out, int out_size, void* d_ws, size_t ws_size,
                              hipStream_t stream) {
    const float* gr    = (const float*)d_in[0];
    const float* h0    = (const float*)d_in[1];
    const float* W_ih  = (const float*)d_in[2];
    const float* W_hh  = (const float*)d_in[3];
    const float* b_ih  = (const float*)d_in[4];
    const float* b_hh  = (const float*)d_in[5];
    const float* W_hp  = (const float*)d_in[6];
    const float* b_hp  = (const float*)d_in[7];
    const float* W_emb = (const float*)d_in[8];
    const float* b_emb = (const float*)d_in[9];
    float* out = (float*)d_out;

    unsigned short* WpT = (unsigned short*)d_ws;
    float* bcomb = (float*)((char*)d_ws + (size_t)G4 * KTOT * sizeof(unsigned short));

    prep_kernel<<<(G4 * KTOT) / 256, 256, 0, stream>>>(W_ih, W_hh, b_ih, b_hh, WpT, bcomb);

    (void)hipFuncSetAttribute((const void*)lstm_kernel,
                              hipFuncAttributeMaxDynamicSharedMemorySize, DYN_LDS);

    lstm_kernel<<<BATCH / BROWS, 512, DYN_LDS, stream>>>(
        gr, h0, WpT, bcomb, W_hp, b_hp, W_emb, b_emb, out);
}

// Round 7
// 388.709 us; speedup vs baseline: 2.3564x; 1.2954x over previous
//
#include <hip/hip_runtime.h>
#include <hip/hip_bf16.h>

// LSTM decoder: 12 steps, batch 32768, hidden 256, input 64, TF=1.
// One persistent block per 128 batch rows (256 blocks = 256 CUs).
// h double-buffered in LDS (bf16), c pinned in AGPRs, weights repacked into
// a per-wave contiguous fragment stream (walking pointer, reg double-buffer).
// TRANSPOSED mfma (A=weights, B=h). Pass = (ch, batch-half) with ALL 4 gates
// in-register (acc 64) -> LDS A-reads halved vs gate-split; full cell update
// per pass (no sigmoid carry). Fast sigmoid/tanh via raw v_exp/v_rcp.
// h-write packing via v_cvt_pk_bf16_f32. Out-projection via MFMA.

#define PRED_LEN 12
#define BATCH    32768
#define HID      256
#define IDIM     64
#define KTOT     320
#define G4       1024
#define BROWS    128
#define HSTR     264      // padded bf16 row stride
#define XSTR     72

#define DYN_LDS  ((2 * BROWS * HSTR + BROWS * XSTR) * 2)   // 153600 B

typedef short s16x8 __attribute__((ext_vector_type(8)));
typedef short s16x4 __attribute__((ext_vector_type(4)));
typedef float f32x4 __attribute__((ext_vector_type(4)));

#define LOG2E 1.44269504088896340736f

static __device__ __forceinline__ float fexp2(float x) {
    float r; asm("v_exp_f32 %0, %1" : "=v"(r) : "v"(x)); return r;
}
static __device__ __forceinline__ float frcp(float x) {
    float r; asm("v_rcp_f32 %0, %1" : "=v"(r) : "v"(x)); return r;
}
static __device__ __forceinline__ float sigmoid_f(float x) {
    return frcp(1.0f + fexp2(-LOG2E * x));           // 1/(1+e^-x)
}
static __device__ __forceinline__ float tanh_f(float x) {
    return fmaf(-2.0f, frcp(1.0f + fexp2(2.0f * LOG2E * x)), 1.0f);
}
static __device__ __forceinline__ unsigned int pk2bf(float a, float b) {
    unsigned int r;
    asm("v_cvt_pk_bf16_f32 %0, %1, %2" : "=v"(r) : "v"(a), "v"(b));
    return r;   // lo = bf16(a), hi = bf16(b)
}
static __device__ __forceinline__ unsigned short f2bf(float x) {
    __hip_bfloat16 h = __float2bfloat16(x);
    return *reinterpret_cast<unsigned short*>(&h);
}

static __device__ __forceinline__ void ag_write(float& dst, float v) {
    asm("v_accvgpr_write_b32 %0, %1" : "=a"(dst) : "v"(v));
}
static __device__ __forceinline__ float ag_read(float src) {
    float r;
    asm("v_accvgpr_read_b32 %0, %1" : "=v"(r) : "a"(src));
    return r;
}

// WpT short index = ((((w*2 + ch)*10 + kf)*4 + g)*64 + lane)*8 + e
// value = W[g*256 + ch*128 + w*16 + (lane&15)][kf*32 + (lane>>4)*8 + e]
// with W = [W_hh | W_ih] along k. 327680 shorts = 640 KB.
__global__ void prep_kernel(const float* __restrict__ W_ih,
                            const float* __restrict__ W_hh,
                            const float* __restrict__ b_ih,
                            const float* __restrict__ b_hh,
                            unsigned short* __restrict__ WpT,
                            float* __restrict__ bcomb) {
    int gid = blockIdx.x * 256 + threadIdx.x;     // 0 .. 327679
    int e    = gid & 7;
    int lane = (gid >> 3) & 63;
    int g    = (gid >> 9) & 3;
    int q    = gid >> 11;          // (w*2+ch)*10 + kf
    int kf   = q % 10;
    int wch  = q / 10;
    int ch   = wch & 1;
    int w    = wch >> 1;
    int n    = g * 256 + ch * 128 + w * 16 + (lane & 15);
    int k    = kf * 32 + (lane >> 4) * 8 + e;
    float v  = (k < HID) ? W_hh[n * HID + k] : W_ih[n * IDIM + (k - HID)];
    WpT[gid] = f2bf(v);
    if (gid < G4) bcomb[gid] = b_ih[gid] + b_hh[gid];
}

__global__ __launch_bounds__(512, 2) void lstm_kernel(
    const float* __restrict__ gr,      // (13, B, 2)
    const float* __restrict__ h0g,     // (B, 256)
    const unsigned short* __restrict__ WpT,
    const float* __restrict__ bcomb,   // (1024,)
    const float* __restrict__ W_hp,    // (2, 256)
    const float* __restrict__ b_hp,    // (2,)
    const float* __restrict__ W_emb,   // (64, 2)
    const float* __restrict__ b_emb,   // (64,)
    float* __restrict__ out)           // (12, B, 2)
{
    extern __shared__ unsigned short smem[];
    unsigned short* hb0 = smem;                        // [BROWS][HSTR]
    unsigned short* hb1 = smem + BROWS * HSTR;
    unsigned short* xb  = smem + 2 * BROWS * HSTR;     // [BROWS][XSTR]

    __shared__ float sWe0[IDIM], sWe1[IDIM], sBe[IDIM];
    __shared__ unsigned short sWhpb[2 * HSTR];
    __shared__ float sBiasT[8 * 2 * 4 * 16];  // [wave][ch][g][u]

    const int tid  = threadIdx.x;
    const int wave = tid >> 6;
    const int lane = tid & 63;
    const int l15  = lane & 15;
    const int lq   = lane >> 4;
    const int row0 = blockIdx.x * BROWS;

    if (tid < IDIM) {
        sWe0[tid] = W_emb[tid * 2 + 0];
        sWe1[tid] = W_emb[tid * 2 + 1];
        sBe[tid]  = b_emb[tid];
    }
    {
        int r = tid >> 8, c = tid & 255;
        sWhpb[r * HSTR + c] = f2bf(W_hp[r * HID + c]);
    }
#pragma unroll
    for (int j = tid; j < 8 * 2 * 4 * 16; j += 512) {
        int w   = j >> 7;
        int rem = j & 127;
        int ch  = rem >> 6;
        int g   = (rem >> 4) & 3;
        int u   = rem & 15;
        sBiasT[j] = bcomb[g * HID + ch * 128 + w * 16 + u];
    }

    const float bhp0 = b_hp[0];
    const float bhp1 = b_hp[1];

    // stage h0 (fp32 global -> bf16 LDS hb0)
#pragma unroll
    for (int j = 0; j < 16; ++j) {
        int idx = j * 2048 + tid * 4;
        const float4 v = *reinterpret_cast<const float4*>(&h0g[row0 * HID + idx]);
        int r = idx >> 8;
        int c = idx & 255;
        unsigned int p0 = pk2bf(v.x, v.y);
        unsigned int p1 = pk2bf(v.z, v.w);
        *reinterpret_cast<uint2*>(&hb0[r * HSTR + c]) = make_uint2(p0, p1);
    }

    // inline embedding: x[t] = gr[t+1] @ W_emb^T + b_emb  -> bf16 LDS
    auto stage_x = [&](int tt) {
        const int rr = tid >> 2;
        const int d0 = (tid & 3) * 16;
        const float2 g2 = *reinterpret_cast<const float2*>(
            &gr[(((size_t)(tt + 1)) * BATCH + row0 + rr) * 2]);
        unsigned int pk[8];
#pragma unroll
        for (int e2 = 0; e2 < 8; ++e2) {
            int d = d0 + e2 * 2;
            float a = g2.x * sWe0[d]     + g2.y * sWe1[d]     + sBe[d];
            float b = g2.x * sWe0[d + 1] + g2.y * sWe1[d + 1] + sBe[d + 1];
            pk[e2] = pk2bf(a, b);
        }
        *reinterpret_cast<uint4*>(&xb[rr * XSTR + d0]) =
            make_uint4(pk[0], pk[1], pk[2], pk[3]);
        *reinterpret_cast<uint4*>(&xb[rr * XSTR + d0 + 8]) =
            make_uint4(pk[4], pk[5], pk[6], pk[7]);
    };

    __syncthreads();
    stage_x(0);
    __syncthreads();

    // persistent cell state, fp32, pinned in AGPRs. Index ((ch*2+mh)*4+m)*4+r.
    float cst[64];
#pragma unroll
    for (int i = 0; i < 64; ++i) ag_write(cst[i], 0.0f);

    const s16x8* wvb = reinterpret_cast<const s16x8*>(WpT) + lane;

    unsigned short* hread  = hb0;
    unsigned short* hwrite = hb1;

    for (int t = 0; t < PRED_LEN; ++t) {
        const unsigned short* hA = hread + l15 * HSTR + lq * 8;
        const unsigned short* xA = xb + l15 * XSTR + lq * 8;

#pragma unroll
        for (int ch = 0; ch < 2; ++ch) {
#pragma unroll
            for (int mh = 0; mh < 2; ++mh) {
                const float* bt = &sBiasT[(wave * 2 + ch) * 64 + lq * 4];
                f32x4 acc[4][4];
#pragma unroll
                for (int g = 0; g < 4; ++g) {
                    f32x4 b4 = *reinterpret_cast<const f32x4*>(&bt[g * 16]);
#pragma unroll
                    for (int m = 0; m < 4; ++m) acc[m][g] = b4;
                }

                const s16x8* wp = wvb + ((wave * 2 + ch) * 10) * 256;
                s16x8 wc0 = wp[0], wc1 = wp[64], wc2 = wp[128], wc3 = wp[192];
                wp += 256;

#pragma unroll 1
                for (int kf = 0; kf < 8; ++kf) {
                    s16x8 wn0 = wp[0], wn1 = wp[64], wn2 = wp[128], wn3 = wp[192];
                    wp += 256;
                    const unsigned short* ha = hA + mh * (4 * 16 * HSTR) + kf * 32;
#pragma unroll
                    for (int m = 0; m < 4; ++m) {
                        s16x8 afr = *reinterpret_cast<const s16x8*>(&ha[m * 16 * HSTR]);
                        acc[m][0] = __builtin_amdgcn_mfma_f32_16x16x32_bf16(wc0, afr, acc[m][0], 0, 0, 0);
                        acc[m][1] = __builtin_amdgcn_mfma_f32_16x16x32_bf16(wc1, afr, acc[m][1], 0, 0, 0);
                        acc[m][2] = __builtin_amdgcn_mfma_f32_16x16x32_bf16(wc2, afr, acc[m][2], 0, 0, 0);
                        acc[m][3] = __builtin_amdgcn_mfma_f32_16x16x32_bf16(wc3, afr, acc[m][3], 0, 0, 0);
                    }
                    wc0 = wn0; wc1 = wn1; wc2 = wn2; wc3 = wn3;
                }
                // x tail: kf 8 (load next), kf 9 (no load)
                {
                    s16x8 wn0 = wp[0], wn1 = wp[64], wn2 = wp[128], wn3 = wp[192];
                    const unsigned short* xa = xA + mh * (4 * 16 * XSTR);
#pragma unroll
                    for (int m = 0; m < 4; ++m) {
                        s16x8 afr = *reinterpret_cast<const s16x8*>(&xa[m * 16 * XSTR]);
                        acc[m][0] = __builtin_amdgcn_mfma_f32_16x16x32_bf16(wc0, afr, acc[m][0], 0, 0, 0);
                        acc[m][1] = __builtin_amdgcn_mfma_f32_16x16x32_bf16(wc1, afr, acc[m][1], 0, 0, 0);
                        acc[m][2] = __builtin_amdgcn_mfma_f32_16x16x32_bf16(wc2, afr, acc[m][2], 0, 0, 0);
                        acc[m][3] = __builtin_amdgcn_mfma_f32_16x16x32_bf16(wc3, afr, acc[m][3], 0, 0, 0);
                    }
#pragma unroll
                    for (int m = 0; m < 4; ++m) {
                        s16x8 afr = *reinterpret_cast<const s16x8*>(&xa[m * 16 * XSTR + 32]);
                        acc[m][0] = __builtin_amdgcn_mfma_f32_16x16x32_bf16(wn0, afr, acc[m][0], 0, 0, 0);
                        acc[m][1] = __builtin_amdgcn_mfma_f32_16x16x32_bf16(wn1, afr, acc[m][1], 0, 0, 0);
                        acc[m][2] = __builtin_amdgcn_mfma_f32_16x16x32_bf16(wn2, afr, acc[m][2], 0, 0, 0);
                        acc[m][3] = __builtin_amdgcn_mfma_f32_16x16x32_bf16(wn3, afr, acc[m][3], 0, 0, 0);
                    }
                }

                // full cell update for this (ch, batch-half); 16 elements
                const int nbase = ch * 128 + wave * 16 + lq * 4;
#pragma unroll
                for (int m = 0; m < 4; ++m) {
                    float hv[4];
#pragma unroll
                    for (int r = 0; r < 4; ++r) {
                        int ci = ((ch * 2 + mh) * 4 + m) * 4 + r;
                        float iv = acc[m][0][r];
                        float fv = acc[m][1][r];
                        float gv = acc[m][2][r];
                        float ov = acc[m][3][r];
                        float cn = sigmoid_f(fv) * ag_read(cst[ci]) +
                                   sigmoid_f(iv) * tanh_f(gv);
                        ag_write(cst[ci], cn);
                        hv[r] = sigmoid_f(ov) * tanh_f(cn);
                    }
                    unsigned int p0 = pk2bf(hv[0], hv[1]);
                    unsigned int p1 = pk2bf(hv[2], hv[3]);
                    *reinterpret_cast<uint2*>(
                        &hwrite[((mh * 4 + m) * 16 + l15) * HSTR + nbase]) =
                        make_uint2(p0, p1);
                }
            }
        }
        __syncthreads();   // h_new complete; old h/x reads complete

        // out[t] = h_new @ W_hp^T + b_hp via MFMA (A rows 0,1 = channels)
        {
            f32x4 po = (f32x4){0.f, 0.f, 0.f, 0.f};
            const unsigned short* hB = hwrite + (wave * 16 + l15) * HSTR + lq * 8;
            const unsigned short* aW = sWhpb + (l15 & 1) * HSTR + lq * 8;
#pragma unroll
            for (int kf = 0; kf < 8; ++kf) {
                s16x8 a = *reinterpret_cast<const s16x8*>(&aW[kf * 32]);
                s16x8 b = *reinterpret_cast<const s16x8*>(&hB[kf * 32]);
                po = __builtin_amdgcn_mfma_f32_16x16x32_bf16(a, b, po, 0, 0, 0);
            }
            if (lq == 0) {
                float2 o2 = make_float2(po[0] + bhp0, po[1] + bhp1);
                *reinterpret_cast<float2*>(
                    &out[((size_t)t * BATCH + row0 + wave * 16 + l15) * 2]) = o2;
            }
        }

        if (t + 1 < PRED_LEN) stage_x(t + 1);
        __syncthreads();   // x[t+1] staged; h_new reads complete

        unsigned short* tmp = hread; hread = hwrite; hwrite = tmp;
    }
}

extern "C" void kernel_launch(void* const* d_in, const int* in_sizes, int n_in,
                              void* d_out, int out_size, void* d_ws, size_t ws_size,
                              hipStream_t stream) {
    const float* gr    = (const float*)d_in[0];
    const float* h0    = (const float*)d_in[1];
    const float* W_ih  = (const float*)d_in[2];
    const float* W_hh  = (const float*)d_in[3];
    const float* b_ih  = (const float*)d_in[4];
    const float* b_hh  = (const float*)d_in[5];
    const float* W_hp  = (const float*)d_in[6];
    const float* b_hp  = (const float*)d_in[7];
    const float* W_emb = (const float*)d_in[8];
    const float* b_emb = (const float*)d_in[9];
    float* out = (float*)d_out;

    unsigned short* WpT = (unsigned short*)d_ws;
    float* bcomb = (float*)((char*)d_ws + (size_t)G4 * KTOT * sizeof(unsigned short));

    prep_kernel<<<(G4 * KTOT) / 256, 256, 0, stream>>>(W_ih, W_hh, b_ih, b_hh, WpT, bcomb);

    (void)hipFuncSetAttribute((const void*)lstm_kernel,
                              hipFuncAttributeMaxDynamicSharedMemorySize, DYN_LDS);

    lstm_kernel<<<BATCH / BROWS, 512, DYN_LDS, stream>>>(
        gr, h0, WpT, bcomb, W_hp, b_hp, W_emb, b_emb, out);
}